// Round 6
// baseline (432.436 us; speedup 1.0000x reference)
//
#include <hip/hip_runtime.h>
#include <math.h>

typedef unsigned int uint;
typedef unsigned short ushort;
typedef unsigned long long u64;
typedef __attribute__((ext_vector_type(8))) short short8;
typedef __attribute__((ext_vector_type(4))) float f32x4;

// Problem: z (16,256,32,32) fp32, emb (8192,256) fp32. N=16384 rows, K=256, C=8192 codes.
// out (fp32): [0,4194304) z_q (b,c,h,w) | [4194304] loss | [4194305,+16384) idx as float
//
// Pipeline: bf16-MFMA screen (fragment-packed operands; A direct-from-global,
// B LDS-staged) -> per-row per-16col-group max (gmax) -> wave-per-row select
// within margin of global max -> exact fp32 rescore (validated sequential-k
// numerics, d = fl32(sumz - 2*dot)) -> u64 (score|idx) min, lowest-index ties.
//
// Fragment packing (16x16x32 MFMA): 1KB frag = 16 rows x 32 k bf16, lane-major:
//   frag(n16 = n>>4, c32 = k>>5); ushort off = (n&15)*8 + ((k>>3)&3)*128 + (k&7)
//   -> wave reads one frag as a single coalesced 1KB load (lane*16B).
//
// ws: zt fp32[16384][256] @0 | zpk 8MB | epk 4MB | sumz | gmax f32[16384][512] | best | loss
#define WS_ZT   0ull
#define WS_ZPK  16777216ull
#define WS_EPK  25165824ull
#define WS_SUMZ 29360128ull
#define WS_GMAX 29425664ull
#define WS_BEST 62980096ull
#define WS_LOSS 63111168ull

#define DOT_MARGIN 3e-4f   // validated: >= 2*max bf16 screening err with big safety

__device__ __forceinline__ ushort f2bf(float f) {           // RNE fp32->bf16
  uint b = __float_as_uint(f);
  b += 0x7fffu + ((b >> 16) & 1u);
  return (ushort)(b >> 16);
}
__device__ __forceinline__ uint ford(float f) {             // orderable uint
  uint b = __float_as_uint(f);
  return (b & 0x80000000u) ? ~b : (b | 0x80000000u);
}
__device__ __forceinline__ void gload_lds16(const void* g, void* l) {
  __builtin_amdgcn_global_load_lds(
      (const __attribute__((address_space(1))) unsigned int*)g,
      (__attribute__((address_space(3))) unsigned int*)l, 16, 0, 0);
}

// ---------------- prep: zt[n][k] fp32 + zpk fragment-packed bf16
__global__ __launch_bounds__(256) void prep_z(const float* __restrict__ z,
                                              float* __restrict__ zt,
                                              ushort* __restrict__ zpk) {
  __shared__ float tile[64][65];
  const int bid = blockIdx.x;
  const int kt = bid & 3, hwt = (bid >> 2) & 15, b = bid >> 6;
  const int t = threadIdx.x, lane = t & 63, grp = t >> 6;
  const float* src = z + b * 262144 + (kt * 64) * 1024 + hwt * 64;
  for (int kk = grp; kk < 64; kk += 4)
    tile[kk][lane] = src[kk * 1024 + lane];                 // coalesced over hw
  __syncthreads();
  for (int rr = grp; rr < 64; rr += 4) {                    // zt: coalesced over k
    const int n = b * 1024 + hwt * 64 + rr;
    zt[n * 256 + kt * 64 + lane] = tile[lane][rr];
  }
  for (int u = t; u < 512; u += 256) {                      // zpk: 16B frag pieces
    const int n_loc = u & 63, kg = u >> 6;
    const int n = b * 1024 + hwt * 64 + n_loc;
    const int k0 = kt * 64 + kg * 8;
    short8 s;
#pragma unroll
    for (int j = 0; j < 8; ++j) s[j] = (short)f2bf(tile[kg * 8 + j][n_loc]);
    *(short8*)(zpk + (size_t)(n >> 4) * 4096 + (k0 >> 5) * 512 +
               ((k0 >> 3) & 3) * 128 + (n & 15) * 8) = s;
  }
}

// ---------------- prep: epk fragment-packed bf16 codebook
__global__ __launch_bounds__(256) void prep_e(const float* __restrict__ emb,
                                              ushort* __restrict__ epk) {
  const int u = blockIdx.x * 256 + threadIdx.x;             // 262144 threads
  const int c = u >> 5, k0 = (u & 31) * 8;
  const float4 v0 = *(const float4*)(emb + c * 256 + k0);
  const float4 v1 = *(const float4*)(emb + c * 256 + k0 + 4);
  short8 s;
  s[0] = (short)f2bf(v0.x); s[1] = (short)f2bf(v0.y);
  s[2] = (short)f2bf(v0.z); s[3] = (short)f2bf(v0.w);
  s[4] = (short)f2bf(v1.x); s[5] = (short)f2bf(v1.y);
  s[6] = (short)f2bf(v1.z); s[7] = (short)f2bf(v1.w);
  *(short8*)(epk + (size_t)(c >> 4) * 4096 + (k0 >> 5) * 512 +
             ((k0 >> 3) & 3) * 128 + (c & 15) * 8) = s;
}

// ---------------- sumz[n] = ||z_n||^2, sequential-k fp32 (validated numerics)
__global__ __launch_bounds__(256) void zsum_kernel(const float* __restrict__ z,
                                                   float* __restrict__ sumz) {
  const int n = (blockIdx.x << 8) + threadIdx.x;
  const int b = n >> 10, hw = n & 1023;
  const float* zb = z + b * 262144 + hw;
  float s = 0.f;
#pragma unroll 8
  for (int c = 0; c < 256; ++c) { const float v = zb[c << 10]; s += v * v; }
  sumz[n] = s;
}

// ---------------- screening GEMM: A register-direct (coalesced frags), B via LDS
// 8192 blocks: XCD x owns col-tiles [8x,8x+8) -> B panels L2-resident per XCD.
__global__ __launch_bounds__(256) void gemm_screen(const ushort* __restrict__ zpk,
                                                   const ushort* __restrict__ epk,
                                                   float* __restrict__ gmax) {
  __shared__ ushort Bs[8192];    // 16 KB: 16 frags x 1KB, stride-1 b128 reads
  __shared__ float sgm[1152];    // [row][grp] stride 9 -> conflict-free
  const int t = threadIdx.x;
  const int w = t >> 6, lane = t & 63;
  const int bid = blockIdx.x;
  const int x = bid & 7, g = bid >> 3;
  const int rowt = g >> 3;                 // 0..127
  const int colt = x * 8 + (g & 7);        // 0..63
  const int n0 = rowt << 7;
  const int wr = w & 1, wc = w >> 1;       // 2x2 wave grid, 64x64 per wave
  const int m16 = lane & 15, q = lane >> 4;

  f32x4 acc[4][4];
#pragma unroll
  for (int i = 0; i < 4; ++i)
#pragma unroll
    for (int j = 0; j < 4; ++j) acc[i][j] = {0.f, 0.f, 0.f, 0.f};

  for (int p = 0; p < 4; ++p) {            // K panels of 64 (2 frags deep)
    if (p) __syncthreads();                // all waves done reading Bs(p-1)
    // stage 16 B frags (4 per wave), each a coalesced 1KB global->LDS DMA
#pragma unroll
    for (int cl = 0; cl < 4; ++cl) {
      const int f = w * 4 + cl;            // f = c16loc*2 + c32loc
      const ushort* src = epk + ((size_t)(colt * 8 + (f >> 1)) * 8 + p * 2 + (f & 1)) * 512 + lane * 8;
      gload_lds16(src, (char*)Bs + f * 1024);
    }
    // A frags direct to registers: coalesced 1KB loads, L2-hot
    short8 av[8];
#pragma unroll
    for (int i = 0; i < 8; ++i) {          // i = s2*4 + ii
      const int ii = i & 3, s2 = i >> 2;
      av[i] = *(const short8*)(zpk + ((size_t)(rowt * 8 + wr * 4 + ii) * 8 + p * 2 + s2) * 512 + lane * 8);
    }
    __syncthreads();                       // Bs(p) ready (vmcnt drained)
#pragma unroll
    for (int s2 = 0; s2 < 2; ++s2) {
      short8 bv[4];
#pragma unroll
      for (int j = 0; j < 4; ++j)
        bv[j] = *(const short8*)&Bs[(size_t)((wc * 4 + j) * 2 + s2) * 512 + lane * 8];
#pragma unroll
      for (int ii = 0; ii < 4; ++ii)
#pragma unroll
        for (int j = 0; j < 4; ++j)
          acc[ii][j] = __builtin_amdgcn_mfma_f32_16x16x32_bf16(av[s2 * 4 + ii], bv[j], acc[ii][j], 0, 0, 0);
    }
  }

  // ---- epilogue: per-row max over each 16-col group
  __syncthreads();
#pragma unroll
  for (int i = 0; i < 4; ++i)
#pragma unroll
    for (int j = 0; j < 4; ++j)
#pragma unroll
      for (int reg = 0; reg < 4; ++reg) {
        float m = acc[i][j][reg];
        m = fmaxf(m, __shfl_xor(m, 1, 64));
        m = fmaxf(m, __shfl_xor(m, 2, 64));
        m = fmaxf(m, __shfl_xor(m, 4, 64));
        m = fmaxf(m, __shfl_xor(m, 8, 64));   // group max over 16 col-lanes
        if (m16 == 0)
          sgm[(wr * 64 + i * 16 + q * 4 + reg) * 9 + wc * 4 + j] = m;
      }
  __syncthreads();
  { // coalesced store: gmax[(n0+row)*512 + colt*8 + grp]
    const int row = t >> 1, gb = (t & 1) * 4;
    float4 v;
    v.x = sgm[row * 9 + gb];     v.y = sgm[row * 9 + gb + 1];
    v.z = sgm[row * 9 + gb + 2]; v.w = sgm[row * 9 + gb + 3];
    *(float4*)&gmax[(size_t)(n0 + row) * 512 + colt * 8 + gb] = v;
  }
}

// ---------------- wave-per-row: global max over 512 groups -> exact rescore of hits
__global__ __launch_bounds__(256) void select_rescore(const float* __restrict__ gmax,
                                                      const float* __restrict__ zt,
                                                      const float* __restrict__ emb,
                                                      const float* __restrict__ sumz,
                                                      u64* __restrict__ best) {
  const int t = threadIdx.x, w = t >> 6, lane = t & 63;
  const int n = (blockIdx.x << 2) + w;     // one wave per row, no __syncthreads
  __shared__ float zrow[4][256];
  __shared__ ushort hits[4][64];
  __shared__ int nh[4];
  if (lane == 0) nh[w] = 0;
  ((float4*)zrow[w])[lane] = ((const float4*)(zt + (size_t)n * 256))[lane];
  const float4 g0 = ((const float4*)(gmax + (size_t)n * 512))[lane];
  const float4 g1 = ((const float4*)(gmax + (size_t)n * 512))[lane + 64];
  float m = fmaxf(fmaxf(fmaxf(g0.x, g0.y), fmaxf(g0.z, g0.w)),
                  fmaxf(fmaxf(g1.x, g1.y), fmaxf(g1.z, g1.w)));
#pragma unroll
  for (int off = 1; off < 64; off <<= 1) m = fmaxf(m, __shfl_xor(m, off, 64));
  const float thr = m - DOT_MARGIN;
  {
    const float gv[8] = {g0.x, g0.y, g0.z, g0.w, g1.x, g1.y, g1.z, g1.w};
#pragma unroll
    for (int j = 0; j < 8; ++j)
      if (gv[j] >= thr) {
        const int gid = (j < 4) ? lane * 4 + j : 256 + lane * 4 + (j - 4);
        const int p = atomicAdd(&nh[w], 1);
        if (p < 64) hits[w][p] = (ushort)gid;
      }
  }
  __threadfence_block();
  int K = nh[w]; if (K > 64) K = 64;
  const float sz = sumz[n];
  u64 bk = ~0ull;
  for (int id = lane; id < K * 16; id += 64) {
    const int c = hits[w][id >> 4] * 16 + (id & 15);
    const float4* ea = (const float4*)(emb + c * 256);
    const float4* za = (const float4*)zrow[w];
    float sdot = 0.f;
#pragma unroll 8
    for (int k = 0; k < 64; ++k) {          // validated sequential-k fp32 numerics
      const float4 a = za[k], e = ea[k];
      sdot = fmaf(a.x, e.x, sdot); sdot = fmaf(a.y, e.y, sdot);
      sdot = fmaf(a.z, e.z, sdot); sdot = fmaf(a.w, e.w, sdot);
    }
    const float d = sz - 2.f * sdot;
    const u64 key = ((u64)ford(d) << 32) | (uint)c;
    if (key < bk) bk = key;
  }
#pragma unroll
  for (int off = 1; off < 64; off <<= 1) {
    const u64 o = (((u64)(uint)__shfl_xor((int)(bk >> 32), off, 64)) << 32) |
                  (uint)__shfl_xor((int)(bk & 0xffffffffu), off, 64);
    if (o < bk) bk = o;
  }
  if (lane == 0) best[n] = bk;              // single owner, plain store
}

// ---------------- gather z_q, idx, loss (validated)
__global__ __launch_bounds__(256) void gather_kernel(const float* __restrict__ z,
                                                     const float* __restrict__ emb,
                                                     const u64* __restrict__ best,
                                                     float* __restrict__ out,
                                                     double* __restrict__ loss_acc) {
  const int t = threadIdx.x;
  const int n0 = blockIdx.x << 6;
  const int n = n0 + (t & 63);
  const int idx = (int)(best[n] & 0xffffffffull);
  const int b_i = n >> 10, hw = n & 1023;
  const int c0 = t >> 6;
  const float* zb = z + b_i * 262144 + hw;
  float* ob = out + b_i * 262144 + hw;
  const float* eb = emb + idx * 256;
  float lsum = 0.f;
#pragma unroll 4
  for (int c = c0; c < 256; c += 4) {
    const float ev = eb[c];
    const float zv = zb[c << 10];
    ob[c << 10] = ev;
    const float d = ev - zv;
    lsum += d * d;
  }
  if (c0 == 0) out[4194305 + n] = (float)idx;
#pragma unroll
  for (int off = 32; off; off >>= 1) lsum += __shfl_down(lsum, off, 64);
  __shared__ double wsum[4];
  if ((t & 63) == 0) wsum[t >> 6] = (double)lsum;
  __syncthreads();
  if (t == 0) atomicAdd(loss_acc, wsum[0] + wsum[1] + wsum[2] + wsum[3]);
}

__global__ void finalize_kernel(const double* __restrict__ loss_acc, float* __restrict__ out) {
  if (threadIdx.x == 0) out[4194304] = (float)(1.25 * (*loss_acc) / 4194304.0);
}

// ---------------- launch
extern "C" void kernel_launch(void* const* d_in, const int* in_sizes, int n_in,
                              void* d_out, int out_size, void* d_ws, size_t ws_size,
                              hipStream_t stream) {
  const float* z = (const float*)d_in[0];
  const float* emb = (const float*)d_in[1];
  float* out = (float*)d_out;
  char* ws = (char*)d_ws;
  float* zt = (float*)(ws + WS_ZT);
  ushort* zpk = (ushort*)(ws + WS_ZPK);
  ushort* epk = (ushort*)(ws + WS_EPK);
  float* sumz = (float*)(ws + WS_SUMZ);
  float* gmax = (float*)(ws + WS_GMAX);
  u64* best = (u64*)(ws + WS_BEST);
  double* loss_acc = (double*)(ws + WS_LOSS);

  hipMemsetAsync(loss_acc, 0, sizeof(double), stream);
  prep_z<<<1024, 256, 0, stream>>>(z, zt, zpk);
  prep_e<<<1024, 256, 0, stream>>>(emb, epk);
  zsum_kernel<<<64, 256, 0, stream>>>(z, sumz);
  gemm_screen<<<8192, 256, 0, stream>>>(zpk, epk, gmax);
  select_rescore<<<4096, 256, 0, stream>>>(gmax, zt, emb, sumz, best);
  gather_kernel<<<256, 256, 0, stream>>>(z, emb, best, out, loss_acc);
  finalize_kernel<<<1, 64, 0, stream>>>(loss_acc, out);
}

// Round 7
// 326.044 us; speedup vs baseline: 1.3263x; 1.3263x over previous
//
#include <hip/hip_runtime.h>
#include <math.h>

typedef unsigned int uint;
typedef unsigned short ushort;
typedef unsigned long long u64;
typedef __attribute__((ext_vector_type(8))) short short8;
typedef __attribute__((ext_vector_type(4))) float f32x4;

// Problem: z (16,256,32,32) fp32, emb (8192,256) fp32. N=16384 rows, K=256, C=8192 codes.
// out (fp32): [0,4194304) z_q (b,c,h,w) | [4194304] loss | [4194305,+16384) idx as float
//
// Pipeline: bf16-MFMA screen (A=codebook LDS-resident 64KB, B=z streamed, barrier-free
// K-loop) -> per-row per-16col-group max (gmax) -> wave-per-row select within margin
// of global max -> exact fp32 rescore (validated sequential-k numerics,
// d = fl32(sumz - 2*dot)) -> u64 (score|idx) min, lowest-index ties.
//
// Fragment packing (16x16x32 MFMA, operand-symmetric, validated rounds 5-6):
//   frag(t16 = idx>>4, k32 = k>>5) of 512 shorts; off = ((k>>3)&3)*128 + (idx&15)*8 + (k&7)
//   -> lane l holds idx=l&15, k = (l>>4)*8 + j; one frag = coalesced 1KB (lane*16B).
//
// ws: zt fp32[16384][256] @0 | zpk 8MB | epk 4MB | sumz | gmax f32[16384][512] | best | loss
#define WS_ZT   0ull
#define WS_ZPK  16777216ull
#define WS_EPK  25165824ull
#define WS_SUMZ 29360128ull
#define WS_GMAX 29425664ull
#define WS_BEST 62980096ull
#define WS_LOSS 63111168ull

#define DOT_MARGIN 3e-4f   // validated: >= 2*max bf16 screening err with safety

__device__ __forceinline__ ushort f2bf(float f) {           // RNE fp32->bf16
  uint b = __float_as_uint(f);
  b += 0x7fffu + ((b >> 16) & 1u);
  return (ushort)(b >> 16);
}
__device__ __forceinline__ uint ford(float f) {             // orderable uint
  uint b = __float_as_uint(f);
  return (b & 0x80000000u) ? ~b : (b | 0x80000000u);
}
__device__ __forceinline__ void gload_lds16(const void* g, void* l) {
  __builtin_amdgcn_global_load_lds(
      (const __attribute__((address_space(1))) unsigned int*)g,
      (__attribute__((address_space(3))) unsigned int*)l, 16, 0, 0);
}

// ---------------- prep: zt[n][k] fp32 + zpk fragment-packed bf16 (validated)
__global__ __launch_bounds__(256) void prep_z(const float* __restrict__ z,
                                              float* __restrict__ zt,
                                              ushort* __restrict__ zpk) {
  __shared__ float tile[64][65];
  const int bid = blockIdx.x;
  const int kt = bid & 3, hwt = (bid >> 2) & 15, b = bid >> 6;
  const int t = threadIdx.x, lane = t & 63, grp = t >> 6;
  const float* src = z + b * 262144 + (kt * 64) * 1024 + hwt * 64;
  for (int kk = grp; kk < 64; kk += 4)
    tile[kk][lane] = src[kk * 1024 + lane];                 // coalesced over hw
  __syncthreads();
  for (int rr = grp; rr < 64; rr += 4) {                    // zt: coalesced over k
    const int n = b * 1024 + hwt * 64 + rr;
    zt[n * 256 + kt * 64 + lane] = tile[lane][rr];
  }
  for (int u = t; u < 512; u += 256) {                      // zpk: 16B frag pieces
    const int n_loc = u & 63, kg = u >> 6;
    const int n = b * 1024 + hwt * 64 + n_loc;
    const int k0 = kt * 64 + kg * 8;
    short8 s;
#pragma unroll
    for (int j = 0; j < 8; ++j) s[j] = (short)f2bf(tile[kg * 8 + j][n_loc]);
    *(short8*)(zpk + (size_t)(n >> 4) * 4096 + (k0 >> 5) * 512 +
               ((k0 >> 3) & 3) * 128 + (n & 15) * 8) = s;
  }
}

// ---------------- prep: epk fragment-packed bf16 codebook (validated)
__global__ __launch_bounds__(256) void prep_e(const float* __restrict__ emb,
                                              ushort* __restrict__ epk) {
  const int u = blockIdx.x * 256 + threadIdx.x;             // 262144 threads
  const int c = u >> 5, k0 = (u & 31) * 8;
  const float4 v0 = *(const float4*)(emb + c * 256 + k0);
  const float4 v1 = *(const float4*)(emb + c * 256 + k0 + 4);
  short8 s;
  s[0] = (short)f2bf(v0.x); s[1] = (short)f2bf(v0.y);
  s[2] = (short)f2bf(v0.z); s[3] = (short)f2bf(v0.w);
  s[4] = (short)f2bf(v1.x); s[5] = (short)f2bf(v1.y);
  s[6] = (short)f2bf(v1.z); s[7] = (short)f2bf(v1.w);
  *(short8*)(epk + (size_t)(c >> 4) * 4096 + (k0 >> 5) * 512 +
             ((k0 >> 3) & 3) * 128 + (c & 15) * 8) = s;
}

// ---------------- sumz[n] = ||z_n||^2, sequential-k fp32 (validated numerics)
__global__ __launch_bounds__(256) void zsum_kernel(const float* __restrict__ z,
                                                   float* __restrict__ sumz) {
  const int n = (blockIdx.x << 8) + threadIdx.x;
  const int b = n >> 10, hw = n & 1023;
  const float* zb = z + b * 262144 + hw;
  float s = 0.f;
#pragma unroll 8
  for (int c = 0; c < 256; ++c) { const float v = zb[c << 10]; s += v * v; }
  sumz[n] = s;
}

// ---------------- screening GEMM: codebook panel LDS-resident, barrier-free K-loop
// grid 1024 = 16 rowg x 64 colb; bid = (rowg*8 + p)*8 + x, colb = p*8 + x
// -> XCD x keeps its 8 epk panels + zpk slice L2-resident.
// Block: 1024 rows x 128 codes. Waves 2x2: code-half a = w&1, row-half rh = w>>1.
__global__ __launch_bounds__(256) void gemm_screen(const ushort* __restrict__ zpk,
                                                   const ushort* __restrict__ epk,
                                                   float* __restrict__ gmax) {
  __shared__ ushort Cs[32768];   // 64 KB: 64 frags x 1KB, frag f = c16loc*8 + k32
  const int t = threadIdx.x;
  const int w = t >> 6, lane = t & 63;
  const int bid = blockIdx.x;
  const int x = bid & 7, y = bid >> 3;
  const int p = y & 7, rowg = y >> 3;
  const int colb = p * 8 + x;
  const int n0 = rowg << 10;
  const int a = w & 1, rh = w >> 1;
  const int m16 = lane & 15, q = lane >> 4;

  // stage code panel once: 16 coalesced 1KB DMAs per wave
#pragma unroll
  for (int f2 = 0; f2 < 16; ++f2) {
    const int f = w * 16 + f2;
    gload_lds16(epk + (size_t)colb * 32768 + f * 512 + lane * 8, (char*)Cs + f * 1024);
  }
  __syncthreads();                         // only barrier in the kernel

  short8 zc[8], zn[8];                     // z frags: [s2*4 + jr], k64-rotating
  const ushort* zb0 = zpk + ((size_t)(n0 >> 4) + rh * 4) * 4096 + lane * 8;
  // preload strip 0, k32 = 0,1
#pragma unroll
  for (int jr = 0; jr < 4; ++jr)
#pragma unroll
    for (int s = 0; s < 2; ++s)
      zc[s * 4 + jr] = *(const short8*)(zb0 + jr * 4096 + s * 512);

  for (int strip = 0; strip < 8; ++strip) {
    const int rbase = n0 + strip * 128 + rh * 64;
    const ushort* zb = zpk + (size_t)(rbase >> 4) * 4096 + lane * 8;
    f32x4 acc[4][4];                       // [ic][jr]
#pragma unroll
    for (int i = 0; i < 4; ++i)
#pragma unroll
      for (int j = 0; j < 4; ++j) acc[i][j] = {0.f, 0.f, 0.f, 0.f};

#pragma unroll
    for (int ks = 0; ks < 4; ++ks) {       // k64 super-steps
      if (ks < 3) {
#pragma unroll
        for (int jr = 0; jr < 4; ++jr)
#pragma unroll
          for (int s = 0; s < 2; ++s)
            zn[s * 4 + jr] = *(const short8*)(zb + jr * 4096 + ((ks + 1) * 2 + s) * 512);
      }
#pragma unroll
      for (int s = 0; s < 2; ++s) {
        const int k32 = ks * 2 + s;
        short8 cv[4];
#pragma unroll
        for (int ic = 0; ic < 4; ++ic)
          cv[ic] = *(const short8*)&Cs[(size_t)((a * 4 + ic) * 8 + k32) * 512 + lane * 8];
#pragma unroll
        for (int ic = 0; ic < 4; ++ic)
#pragma unroll
          for (int jr = 0; jr < 4; ++jr)
            acc[ic][jr] = __builtin_amdgcn_mfma_f32_16x16x32_bf16(cv[ic], zc[s * 4 + jr],
                                                                  acc[ic][jr], 0, 0, 0);
      }
#pragma unroll
      for (int i = 0; i < 8; ++i) zc[i] = zn[i];
    }

    // prefetch next strip's first k64 BEFORE the epilogue
    if (strip < 7) {
      const ushort* zbn = zpk + (size_t)((rbase + 128) >> 4) * 4096 + lane * 8;
#pragma unroll
      for (int jr = 0; jr < 4; ++jr)
#pragma unroll
        for (int s = 0; s < 2; ++s)
          zc[s * 4 + jr] = *(const short8*)(zbn + jr * 4096 + s * 512);
    }

    // epilogue: D row=code(q*4+reg), col=z-row(m16). Group(16 codes)=tile ic.
    // per (ic,jr): in-lane max over reg + shfl over q-bits (16,32) -> 2 shuffles.
    float v[4][4];
#pragma unroll
    for (int ic = 0; ic < 4; ++ic)
#pragma unroll
      for (int jr = 0; jr < 4; ++jr) {
        float m = fmaxf(fmaxf(acc[ic][jr][0], acc[ic][jr][1]),
                        fmaxf(acc[ic][jr][2], acc[ic][jr][3]));
        m = fmaxf(m, __shfl_xor(m, 16, 64));
        m = fmaxf(m, __shfl_xor(m, 32, 64));
        v[ic][jr] = m;                     // replicated across q lanes
      }
#pragma unroll
    for (int jr = 0; jr < 4; ++jr) {       // lane q stores group ic=q
      const float sv = (q == 0) ? v[0][jr] : (q == 1) ? v[1][jr]
                     : (q == 2) ? v[2][jr] : v[3][jr];
      gmax[(size_t)(rbase + jr * 16 + m16) * 512 + colb * 8 + a * 4 + q] = sv;
    }
  }
}

// ---------------- wave-per-row: global max over 512 groups -> exact rescore of hits
__global__ __launch_bounds__(256) void select_rescore(const float* __restrict__ gmax,
                                                      const float* __restrict__ zt,
                                                      const float* __restrict__ emb,
                                                      const float* __restrict__ sumz,
                                                      u64* __restrict__ best) {
  const int t = threadIdx.x, w = t >> 6, lane = t & 63;
  const int n = (blockIdx.x << 2) + w;     // one wave per row, no __syncthreads
  __shared__ float zrow[4][256];
  __shared__ ushort hits[4][64];
  __shared__ int nh[4];
  if (lane == 0) nh[w] = 0;
  ((float4*)zrow[w])[lane] = ((const float4*)(zt + (size_t)n * 256))[lane];
  const float4 g0 = ((const float4*)(gmax + (size_t)n * 512))[lane];
  const float4 g1 = ((const float4*)(gmax + (size_t)n * 512))[lane + 64];
  float m = fmaxf(fmaxf(fmaxf(g0.x, g0.y), fmaxf(g0.z, g0.w)),
                  fmaxf(fmaxf(g1.x, g1.y), fmaxf(g1.z, g1.w)));
#pragma unroll
  for (int off = 1; off < 64; off <<= 1) m = fmaxf(m, __shfl_xor(m, off, 64));
  const float thr = m - DOT_MARGIN;
  {
    const float gv[8] = {g0.x, g0.y, g0.z, g0.w, g1.x, g1.y, g1.z, g1.w};
#pragma unroll
    for (int j = 0; j < 8; ++j)
      if (gv[j] >= thr) {
        const int gid = (j < 4) ? lane * 4 + j : 256 + lane * 4 + (j - 4);
        const int p = atomicAdd(&nh[w], 1);
        if (p < 64) hits[w][p] = (ushort)gid;
      }
  }
  __threadfence_block();
  int K = nh[w]; if (K > 64) K = 64;
  const float sz = sumz[n];
  u64 bk = ~0ull;
  for (int id = lane; id < K * 16; id += 64) {
    const int c = hits[w][id >> 4] * 16 + (id & 15);
    const float4* ea = (const float4*)(emb + c * 256);
    const float4* za = (const float4*)zrow[w];
    float sdot = 0.f;
#pragma unroll 8
    for (int k = 0; k < 64; ++k) {          // validated sequential-k fp32 numerics
      const float4 a = za[k], e = ea[k];
      sdot = fmaf(a.x, e.x, sdot); sdot = fmaf(a.y, e.y, sdot);
      sdot = fmaf(a.z, e.z, sdot); sdot = fmaf(a.w, e.w, sdot);
    }
    const float d = sz - 2.f * sdot;
    const u64 key = ((u64)ford(d) << 32) | (uint)c;
    if (key < bk) bk = key;
  }
#pragma unroll
  for (int off = 1; off < 64; off <<= 1) {
    const u64 o = (((u64)(uint)__shfl_xor((int)(bk >> 32), off, 64)) << 32) |
                  (uint)__shfl_xor((int)(bk & 0xffffffffu), off, 64);
    if (o < bk) bk = o;
  }
  if (lane == 0) best[n] = bk;              // single owner, plain store
}

// ---------------- gather z_q, idx, loss (validated)
__global__ __launch_bounds__(256) void gather_kernel(const float* __restrict__ z,
                                                     const float* __restrict__ emb,
                                                     const u64* __restrict__ best,
                                                     float* __restrict__ out,
                                                     double* __restrict__ loss_acc) {
  const int t = threadIdx.x;
  const int n0 = blockIdx.x << 6;
  const int n = n0 + (t & 63);
  const int idx = (int)(best[n] & 0xffffffffull);
  const int b_i = n >> 10, hw = n & 1023;
  const int c0 = t >> 6;
  const float* zb = z + b_i * 262144 + hw;
  float* ob = out + b_i * 262144 + hw;
  const float* eb = emb + idx * 256;
  float lsum = 0.f;
#pragma unroll 4
  for (int c = c0; c < 256; c += 4) {
    const float ev = eb[c];
    const float zv = zb[c << 10];
    ob[c << 10] = ev;
    const float d = ev - zv;
    lsum += d * d;
  }
  if (c0 == 0) out[4194305 + n] = (float)idx;
#pragma unroll
  for (int off = 32; off; off >>= 1) lsum += __shfl_down(lsum, off, 64);
  __shared__ double wsum[4];
  if ((t & 63) == 0) wsum[t >> 6] = (double)lsum;
  __syncthreads();
  if (t == 0) atomicAdd(loss_acc, wsum[0] + wsum[1] + wsum[2] + wsum[3]);
}

__global__ void finalize_kernel(const double* __restrict__ loss_acc, float* __restrict__ out) {
  if (threadIdx.x == 0) out[4194304] = (float)(1.25 * (*loss_acc) / 4194304.0);
}

// ---------------- launch
extern "C" void kernel_launch(void* const* d_in, const int* in_sizes, int n_in,
                              void* d_out, int out_size, void* d_ws, size_t ws_size,
                              hipStream_t stream) {
  const float* z = (const float*)d_in[0];
  const float* emb = (const float*)d_in[1];
  float* out = (float*)d_out;
  char* ws = (char*)d_ws;
  float* zt = (float*)(ws + WS_ZT);
  ushort* zpk = (ushort*)(ws + WS_ZPK);
  ushort* epk = (ushort*)(ws + WS_EPK);
  float* sumz = (float*)(ws + WS_SUMZ);
  float* gmax = (float*)(ws + WS_GMAX);
  u64* best = (u64*)(ws + WS_BEST);
  double* loss_acc = (double*)(ws + WS_LOSS);

  hipMemsetAsync(loss_acc, 0, sizeof(double), stream);
  prep_z<<<1024, 256, 0, stream>>>(z, zt, zpk);
  prep_e<<<1024, 256, 0, stream>>>(emb, epk);
  zsum_kernel<<<64, 256, 0, stream>>>(z, sumz);
  gemm_screen<<<1024, 256, 0, stream>>>(zpk, epk, gmax);
  select_rescore<<<4096, 256, 0, stream>>>(gmax, zt, emb, sumz, best);
  gather_kernel<<<256, 256, 0, stream>>>(z, emb, best, out, loss_acc);
  finalize_kernel<<<1, 64, 0, stream>>>(loss_acc, out);
}

// Round 8
// 293.054 us; speedup vs baseline: 1.4756x; 1.1126x over previous
//
#include <hip/hip_runtime.h>
#include <math.h>

typedef unsigned int uint;
typedef unsigned short ushort;
typedef unsigned long long u64;
typedef __attribute__((ext_vector_type(8))) short short8;
typedef __attribute__((ext_vector_type(4))) float f32x4;

// Problem: z (16,256,32,32) fp32, emb (8192,256) fp32. N=16384 rows, K=256, C=8192 codes.
// out (fp32): [0,4194304) z_q (b,c,h,w) | [4194304] loss | [4194305,+16384) idx as float
//
// Pipeline: bf16-MFMA screen (codebook LDS-resident, barrier-free K-loop) ->
// per-row per-8code-group max, 2 groups packed bf16 in u32 (gmax[n][512]) ->
// wave-per-row select within margin of global max -> exact fp32 rescore
// (validated sequential-k numerics, d = fl32(sumz - 2*dot)) -> u64 (score|idx)
// min, lowest-index ties. Margin covers 2*eps_screen + bf16 store rounding.
//
// ws: zt fp32[16384][256] @0 | zpk 8MB | epk 4MB | sumz | gmax u32[16384][512] | best | loss,ctr
#define WS_ZT   0ull
#define WS_ZPK  16777216ull
#define WS_EPK  25165824ull
#define WS_SUMZ 29360128ull
#define WS_GMAX 29425664ull
#define WS_BEST 62980096ull
#define WS_LOSS 63111168ull

#define DOT_MARGIN 3e-4f   // >= 2*eps_screen(2.6e-5) + bf16 ulp(3e-5), 5x safety

__device__ __forceinline__ ushort f2bf(float f) {           // RNE fp32->bf16
  uint b = __float_as_uint(f);
  b += 0x7fffu + ((b >> 16) & 1u);
  return (ushort)(b >> 16);
}
__device__ __forceinline__ uint ford(float f) {             // orderable uint
  uint b = __float_as_uint(f);
  return (b & 0x80000000u) ? ~b : (b | 0x80000000u);
}
__device__ __forceinline__ void gload_lds16(const void* g, void* l) {
  __builtin_amdgcn_global_load_lds(
      (const __attribute__((address_space(1))) unsigned int*)g,
      (__attribute__((address_space(3))) unsigned int*)l, 16, 0, 0);
}

// ---------------- prep: zt[n][k] fp32 + zpk fragment-packed bf16 (validated)
__global__ __launch_bounds__(256) void prep_z(const float* __restrict__ z,
                                              float* __restrict__ zt,
                                              ushort* __restrict__ zpk) {
  __shared__ float tile[64][65];
  const int bid = blockIdx.x;
  const int kt = bid & 3, hwt = (bid >> 2) & 15, b = bid >> 6;
  const int t = threadIdx.x, lane = t & 63, grp = t >> 6;
  const float* src = z + b * 262144 + (kt * 64) * 1024 + hwt * 64;
  for (int kk = grp; kk < 64; kk += 4)
    tile[kk][lane] = src[kk * 1024 + lane];                 // coalesced over hw
  __syncthreads();
  for (int rr = grp; rr < 64; rr += 4) {                    // zt: coalesced over k
    const int n = b * 1024 + hwt * 64 + rr;
    zt[n * 256 + kt * 64 + lane] = tile[lane][rr];
  }
  for (int u = t; u < 512; u += 256) {                      // zpk: 16B frag pieces
    const int n_loc = u & 63, kg = u >> 6;
    const int n = b * 1024 + hwt * 64 + n_loc;
    const int k0 = kt * 64 + kg * 8;
    short8 s;
#pragma unroll
    for (int j = 0; j < 8; ++j) s[j] = (short)f2bf(tile[kg * 8 + j][n_loc]);
    *(short8*)(zpk + (size_t)(n >> 4) * 4096 + (k0 >> 5) * 512 +
               ((k0 >> 3) & 3) * 128 + (n & 15) * 8) = s;
  }
}

// ---------------- prep: epk fragment-packed bf16 codebook (validated)
__global__ __launch_bounds__(256) void prep_e(const float* __restrict__ emb,
                                              ushort* __restrict__ epk) {
  const int u = blockIdx.x * 256 + threadIdx.x;             // 262144 threads
  const int c = u >> 5, k0 = (u & 31) * 8;
  const float4 v0 = *(const float4*)(emb + c * 256 + k0);
  const float4 v1 = *(const float4*)(emb + c * 256 + k0 + 4);
  short8 s;
  s[0] = (short)f2bf(v0.x); s[1] = (short)f2bf(v0.y);
  s[2] = (short)f2bf(v0.z); s[3] = (short)f2bf(v0.w);
  s[4] = (short)f2bf(v1.x); s[5] = (short)f2bf(v1.y);
  s[6] = (short)f2bf(v1.z); s[7] = (short)f2bf(v1.w);
  *(short8*)(epk + (size_t)(c >> 4) * 4096 + (k0 >> 5) * 512 +
             ((k0 >> 3) & 3) * 128 + (c & 15) * 8) = s;
}

// ---------------- sumz[n] = ||z_n||^2, sequential-k fp32 (validated numerics)
__global__ __launch_bounds__(256) void zsum_kernel(const float* __restrict__ z,
                                                   float* __restrict__ sumz) {
  const int n = (blockIdx.x << 8) + threadIdx.x;
  const int b = n >> 10, hw = n & 1023;
  const float* zb = z + b * 262144 + hw;
  float s = 0.f;
#pragma unroll 8
  for (int c = 0; c < 256; ++c) { const float v = zb[c << 10]; s += v * v; }
  sumz[n] = s;
}

// ---------------- screening GEMM: codebook panel LDS-resident, barrier-free K-loop
// (K-loop byte-identical to round-7; only the epilogue changed: 8-group maxes,
//  two bf16 packed per u32, same store count/pattern.)
__global__ __launch_bounds__(256) void gemm_screen(const ushort* __restrict__ zpk,
                                                   const ushort* __restrict__ epk,
                                                   uint* __restrict__ gmax) {
  __shared__ ushort Cs[32768];   // 64 KB: 64 frags x 1KB, frag f = c16loc*8 + k32
  const int t = threadIdx.x;
  const int w = t >> 6, lane = t & 63;
  const int bid = blockIdx.x;
  const int x = bid & 7, y = bid >> 3;
  const int p = y & 7, rowg = y >> 3;
  const int colb = p * 8 + x;
  const int n0 = rowg << 10;
  const int a = w & 1, rh = w >> 1;
  const int m16 = lane & 15, q = lane >> 4;

  // stage code panel once: 16 coalesced 1KB DMAs per wave
#pragma unroll
  for (int f2 = 0; f2 < 16; ++f2) {
    const int f = w * 16 + f2;
    gload_lds16(epk + (size_t)colb * 32768 + f * 512 + lane * 8, (char*)Cs + f * 1024);
  }
  __syncthreads();                         // only barrier in the kernel

  short8 zc[8], zn[8];                     // z frags: [s2*4 + jr], k64-rotating
  const ushort* zb0 = zpk + ((size_t)(n0 >> 4) + rh * 4) * 4096 + lane * 8;
#pragma unroll
  for (int jr = 0; jr < 4; ++jr)
#pragma unroll
    for (int s = 0; s < 2; ++s)
      zc[s * 4 + jr] = *(const short8*)(zb0 + jr * 4096 + s * 512);

  for (int strip = 0; strip < 8; ++strip) {
    const int rbase = n0 + strip * 128 + rh * 64;
    const ushort* zb = zpk + (size_t)(rbase >> 4) * 4096 + lane * 8;
    f32x4 acc[4][4];                       // [ic][jr]
#pragma unroll
    for (int i = 0; i < 4; ++i)
#pragma unroll
      for (int j = 0; j < 4; ++j) acc[i][j] = {0.f, 0.f, 0.f, 0.f};

#pragma unroll
    for (int ks = 0; ks < 4; ++ks) {       // k64 super-steps
      if (ks < 3) {
#pragma unroll
        for (int jr = 0; jr < 4; ++jr)
#pragma unroll
          for (int s = 0; s < 2; ++s)
            zn[s * 4 + jr] = *(const short8*)(zb + jr * 4096 + ((ks + 1) * 2 + s) * 512);
      }
#pragma unroll
      for (int s = 0; s < 2; ++s) {
        const int k32 = ks * 2 + s;
        short8 cv[4];
#pragma unroll
        for (int ic = 0; ic < 4; ++ic)
          cv[ic] = *(const short8*)&Cs[(size_t)((a * 4 + ic) * 8 + k32) * 512 + lane * 8];
#pragma unroll
        for (int ic = 0; ic < 4; ++ic)
#pragma unroll
          for (int jr = 0; jr < 4; ++jr)
            acc[ic][jr] = __builtin_amdgcn_mfma_f32_16x16x32_bf16(cv[ic], zc[s * 4 + jr],
                                                                  acc[ic][jr], 0, 0, 0);
      }
#pragma unroll
      for (int i = 0; i < 8; ++i) zc[i] = zn[i];
    }

    // prefetch next strip's first k64 BEFORE the epilogue
    if (strip < 7) {
      const ushort* zbn = zpk + (size_t)((rbase + 128) >> 4) * 4096 + lane * 8;
#pragma unroll
      for (int jr = 0; jr < 4; ++jr)
#pragma unroll
        for (int s = 0; s < 2; ++s)
          zc[s * 4 + jr] = *(const short8*)(zbn + jr * 4096 + s * 512);
    }

    // epilogue: D row=code(q*4+reg), col=z-row(m16). 8-group g0 = q{0,1} regs,
    // g1 = q{2,3}. in-lane reg-max -> xor16 (8-max) -> xor32 (swap halves) -> pack.
#pragma unroll
    for (int jr = 0; jr < 4; ++jr) {
      uint pk[4];
#pragma unroll
      for (int ic = 0; ic < 4; ++ic) {
        float m = fmaxf(fmaxf(acc[ic][jr][0], acc[ic][jr][1]),
                        fmaxf(acc[ic][jr][2], acc[ic][jr][3]));
        m = fmaxf(m, __shfl_xor(m, 16, 64));     // 8-group max (own half)
        const float o = __shfl_xor(m, 32, 64);   // other half's 8-group max
        const float glo = (q & 2) ? o : m;
        const float ghi = (q & 2) ? m : o;
        pk[ic] = (uint)f2bf(glo) | ((uint)f2bf(ghi) << 16);
      }
      const uint sv = (q == 0) ? pk[0] : (q == 1) ? pk[1] : (q == 2) ? pk[2] : pk[3];
      gmax[(size_t)(rbase + jr * 16 + m16) * 512 + colb * 8 + a * 4 + q] = sv;
    }
  }
}

// ---------------- wave-per-row: global max over 1024 8-groups -> exact rescore of hits
__global__ __launch_bounds__(256) void select_rescore(const uint* __restrict__ gmax,
                                                      const float* __restrict__ zt,
                                                      const float* __restrict__ emb,
                                                      const float* __restrict__ sumz,
                                                      u64* __restrict__ best) {
  const int t = threadIdx.x, w = t >> 6, lane = t & 63;
  const int n = (blockIdx.x << 2) + w;     // one wave per row, no __syncthreads
  __shared__ float zrow[4][256];
  __shared__ ushort hits[4][64];
  __shared__ int nh[4];
  if (lane == 0) nh[w] = 0;
  ((float4*)zrow[w])[lane] = ((const float4*)(zt + (size_t)n * 256))[lane];
  const uint4 r0 = ((const uint4*)(gmax + (size_t)n * 512))[lane];        // u32 4l..
  const uint4 r1 = ((const uint4*)(gmax + (size_t)n * 512))[lane + 64];   // 256+4l..
  const uint uv[8] = {r0.x, r0.y, r0.z, r0.w, r1.x, r1.y, r1.z, r1.w};
  float m = -INFINITY;
#pragma unroll
  for (int j = 0; j < 8; ++j) {
    m = fmaxf(m, __uint_as_float(uv[j] << 16));
    m = fmaxf(m, __uint_as_float(uv[j] & 0xffff0000u));
  }
#pragma unroll
  for (int off = 1; off < 64; off <<= 1) m = fmaxf(m, __shfl_xor(m, off, 64));
  const float thr = m - DOT_MARGIN;
#pragma unroll
  for (int j = 0; j < 8; ++j) {
    const int ui = (j < 4) ? lane * 4 + j : 256 + lane * 4 + (j - 4);
    if (__uint_as_float(uv[j] << 16) >= thr) {
      const int p = atomicAdd(&nh[w], 1);
      if (p < 64) hits[w][p] = (ushort)(ui * 2);
    }
    if (__uint_as_float(uv[j] & 0xffff0000u) >= thr) {
      const int p = atomicAdd(&nh[w], 1);
      if (p < 64) hits[w][p] = (ushort)(ui * 2 + 1);
    }
  }
  __threadfence_block();
  int K = nh[w]; if (K > 64) K = 64;
  const float sz = sumz[n];
  u64 bk = ~0ull;
  for (int id = lane; id < K * 8; id += 64) {
    const int gid = hits[w][id >> 3];
    const int u = gid >> 1, h = gid & 1;
    const int c = (u >> 3) * 128 + (u & 7) * 16 + h * 8 + (id & 7);
    const float4* ea = (const float4*)(emb + c * 256);
    const float4* za = (const float4*)zrow[w];
    float sdot = 0.f;
#pragma unroll 8
    for (int k = 0; k < 64; ++k) {          // validated sequential-k fp32 numerics
      const float4 a = za[k], e = ea[k];
      sdot = fmaf(a.x, e.x, sdot); sdot = fmaf(a.y, e.y, sdot);
      sdot = fmaf(a.z, e.z, sdot); sdot = fmaf(a.w, e.w, sdot);
    }
    const float d = sz - 2.f * sdot;
    const u64 key = ((u64)ford(d) << 32) | (uint)c;
    if (key < bk) bk = key;
  }
#pragma unroll
  for (int off = 1; off < 64; off <<= 1) {
    const u64 o = (((u64)(uint)__shfl_xor((int)(bk >> 32), off, 64)) << 32) |
                  (uint)__shfl_xor((int)(bk & 0xffffffffu), off, 64);
    if (o < bk) bk = o;
  }
  if (lane == 0) best[n] = bk;              // single owner, plain store
}

// ---------------- gather z_q, idx, loss + fused finalize (done-counter)
__global__ __launch_bounds__(256) void gather_kernel(const float* __restrict__ z,
                                                     const float* __restrict__ emb,
                                                     const u64* __restrict__ best,
                                                     float* __restrict__ out,
                                                     double* __restrict__ loss_acc,
                                                     uint* __restrict__ done) {
  const int t = threadIdx.x;
  const int n0 = blockIdx.x << 6;
  const int n = n0 + (t & 63);
  const int idx = (int)(best[n] & 0xffffffffull);
  const int b_i = n >> 10, hw = n & 1023;
  const int c0 = t >> 6;
  const float* zb = z + b_i * 262144 + hw;
  float* ob = out + b_i * 262144 + hw;
  const float* eb = emb + idx * 256;
  float lsum = 0.f;
#pragma unroll 4
  for (int c = c0; c < 256; c += 4) {
    const float ev = eb[c];
    const float zv = zb[c << 10];
    ob[c << 10] = ev;
    const float d = ev - zv;
    lsum += d * d;
  }
  if (c0 == 0) out[4194305 + n] = (float)idx;
#pragma unroll
  for (int off = 32; off; off >>= 1) lsum += __shfl_down(lsum, off, 64);
  __shared__ double wsum[4];
  if ((t & 63) == 0) wsum[t >> 6] = (double)lsum;
  __syncthreads();
  if (t == 0) {
    atomicAdd(loss_acc, wsum[0] + wsum[1] + wsum[2] + wsum[3]);
    __threadfence();
    if (atomicAdd(done, 1u) == 255u) {       // last of 256 blocks
      __threadfence();
      out[4194304] = (float)(1.25 * (*(volatile double*)loss_acc) / 4194304.0);
    }
  }
}

// ---------------- launch
extern "C" void kernel_launch(void* const* d_in, const int* in_sizes, int n_in,
                              void* d_out, int out_size, void* d_ws, size_t ws_size,
                              hipStream_t stream) {
  const float* z = (const float*)d_in[0];
  const float* emb = (const float*)d_in[1];
  float* out = (float*)d_out;
  char* ws = (char*)d_ws;
  float* zt = (float*)(ws + WS_ZT);
  ushort* zpk = (ushort*)(ws + WS_ZPK);
  ushort* epk = (ushort*)(ws + WS_EPK);
  float* sumz = (float*)(ws + WS_SUMZ);
  uint* gmax = (uint*)(ws + WS_GMAX);
  u64* best = (u64*)(ws + WS_BEST);
  double* loss_acc = (double*)(ws + WS_LOSS);
  uint* done = (uint*)(ws + WS_LOSS + 8);

  hipMemsetAsync(ws + WS_LOSS, 0, 16, stream);   // loss_acc + done ctr
  prep_z<<<1024, 256, 0, stream>>>(z, zt, zpk);
  prep_e<<<1024, 256, 0, stream>>>(emb, epk);
  zsum_kernel<<<64, 256, 0, stream>>>(z, sumz);
  gemm_screen<<<1024, 256, 0, stream>>>(zpk, epk, gmax);
  select_rescore<<<4096, 256, 0, stream>>>(gmax, zt, emb, sumz, best);
  gather_kernel<<<256, 256, 0, stream>>>(z, emb, best, out, loss_acc, done);
}